// Round 12
// baseline (373.964 us; speedup 1.0000x reference)
//
#include <hip/hip_runtime.h>
#include <math.h>

#define VOCAB 50000
#define EMB 300
#define NB 128
#define TQ 32
#define TD 4096
#define TOPK 20
#define KP 320               // padded K (10 x 32)
#define NCHUNK 16            // doc chunks (both paths)
#define NHC 75               // EMB/4 (fallback path)
#define QSTRIDE 656          // padded LDS row stride (bytes) for q slab

typedef short short8 __attribute__((ext_vector_type(8)));
typedef float f32x4 __attribute__((ext_vector_type(4)));

// ---- RTNE float -> bf16 helper ----
__device__ inline ushort bf16_rtne(float x) {
  unsigned u = __float_as_uint(x);
  unsigned r = u + 0x7fffu + ((u >> 16) & 1u);
  return (ushort)(r >> 16);
}

// ---------------- Kernel 1 (fallback only): per-row inverse norms ----------------
__global__ __launch_bounds__(256) void rownorm_kernel(const float* __restrict__ emb,
                                                      float* __restrict__ invn) {
  int row = blockIdx.x * 4 + (threadIdx.x >> 6);
  if (row >= VOCAB) return;
  int lane = threadIdx.x & 63;
  float s = 0.f;
  for (int h = lane; h < EMB; h += 64) {
    float v = emb[row * EMB + h];
    s += v * v;
  }
#pragma unroll
  for (int off = 32; off; off >>= 1) s += __shfl_xor(s, off, 64);
  if (lane == 0) invn[row] = 1.0f / fmaxf(sqrtf(s), 1e-8f);
}

// ---------------- MFMA prep: fused norm + bf16(hi) + pad (doc table) ----------------
__global__ __launch_bounds__(256) void dprep_kernel(const float* __restrict__ emb,
                                                    ushort* __restrict__ dhi) {
  int row = blockIdx.x * 4 + (threadIdx.x >> 6);
  if (row >= VOCAB) return;
  int lane = threadIdx.x & 63;
  float v[5];
  float s = 0.f;
#pragma unroll
  for (int j = 0; j < 5; ++j) {
    int k = j * 64 + lane;
    float x = (k < EMB) ? emb[(size_t)row * EMB + k] : 0.f;
    v[j] = x;
    s += x * x;
  }
#pragma unroll
  for (int off = 32; off; off >>= 1) s += __shfl_xor(s, off, 64);
  float inv = 1.0f / fmaxf(sqrtf(s), 1e-8f);
#pragma unroll
  for (int j = 0; j < 5; ++j) {
    int k = j * 64 + lane;
    dhi[(size_t)row * KP + k] = bf16_rtne(v[j] * inv);
  }
}

__global__ __launch_bounds__(256) void qprep2_kernel(const int* __restrict__ query,
                                                     const float* __restrict__ emb,
                                                     ushort* __restrict__ qhi) {
  const int b = blockIdx.x;
  const int wave = (int)threadIdx.x >> 6;
  const int lane = (int)threadIdx.x & 63;
#pragma unroll 1
  for (int q = wave; q < TQ; q += 4) {
    int tok = query[b * TQ + q];
    float v[5];
    float s = 0.f;
#pragma unroll
    for (int j = 0; j < 5; ++j) {
      int k = j * 64 + lane;
      float x = (k < EMB) ? emb[(size_t)tok * EMB + k] : 0.f;
      v[j] = x;
      s += x * x;
    }
#pragma unroll
    for (int off = 32; off; off >>= 1) s += __shfl_xor(s, off, 64);
    float inv = 1.0f / fmaxf(sqrtf(s), 1e-8f);
#pragma unroll
    for (int j = 0; j < 5; ++j) {
      int k = j * 64 + lane;
      qhi[(size_t)(b * TQ + q) * KP + k] = bf16_rtne(v[j] * inv);
    }
  }
}

// ---------------- MFMA main: full-depth gather pipeline (40 in flight) ----------------
// grid (16, NB), block 256 (4 waves). Wave: 32q x 64 tokens, 8 f32x4 acc.
// ALL 40 doc-fragment loads issue in the prologue (10 sets x 4 volatile asm
// global_load_dwordx4 -- 160 VGPR pinned by asm liveness); K-step i waits
// vmcnt(36-4i) then runs its 8 MFMAs. Per-wave MLP: 40 outstanding vs R11's
// ~18 -> per-CU in-flight +78% even at 8 waves/CU. launch_bounds(256,2).
__global__ __launch_bounds__(256, 2) void mfma_topk_kernel(
    const int* __restrict__ doc, const ushort* __restrict__ qhi,
    const ushort* __restrict__ dhi, float* __restrict__ partial) {
  __shared__ __align__(16) char smem[33792];  // qsh (20992B), later costmp
  __shared__ float topv[4][TQ][21];

  float (*costmp)[64][33] = (float (*)[64][33])smem;  // [wave][token][q]

  const int b = blockIdx.y;
  const int chunk = blockIdx.x;
  const int tid = (int)threadIdx.x;
  const int wave = tid >> 6;
  const int lane = tid & 63;
  const int c = lane & 15;
  const int kg = lane >> 4;

  // stage this batch's q-hi slab into LDS (coalesced short8, padded stride)
  {
    const ushort* qsrc = qhi + (size_t)b * TQ * KP;
    for (int i = tid; i < TQ * (KP / 8); i += 256) {
      int row = i / (KP / 8), j = i - row * (KP / 8);
      *(short8*)(smem + row * QSTRIDE + j * 16) =
          *(const short8*)(qsrc + row * KP + j * 8);
    }
  }
  __syncthreads();  // qsh ready

  const int tbase = b * TD + chunk * 256 + wave * 64;
  const ushort* pdh0 = dhi + (size_t)doc[tbase + 0 * 16 + c] * KP + kg * 8;
  const ushort* pdh1 = dhi + (size_t)doc[tbase + 1 * 16 + c] * KP + kg * 8;
  const ushort* pdh2 = dhi + (size_t)doc[tbase + 2 * 16 + c] * KP + kg * 8;
  const ushort* pdh3 = dhi + (size_t)doc[tbase + 3 * 16 + c] * KP + kg * 8;
  const char* qb0 = smem + c * QSTRIDE + kg * 16;
  const char* qb1 = smem + (16 + c) * QSTRIDE + kg * 16;

  f32x4 a00 = {0.f, 0.f, 0.f, 0.f}, a01 = a00, a02 = a00, a03 = a00;
  f32x4 a10 = a00, a11 = a00, a12 = a00, a13 = a00;

#define DECLSET(S) short8 bh0##S, bh1##S, bh2##S, bh3##S;
  DECLSET(A) DECLSET(B) DECLSET(C) DECLSET(D) DECLSET(E)
  DECLSET(F) DECLSET(G) DECLSET(H) DECLSET(I) DECLSET(J)
#undef DECLSET

#define STR2(x) #x
#define STR(x) STR2(x)
#define LD1(DST, PTR, OFFB)                                        \
  asm volatile("global_load_dwordx4 %0, %1, off offset:" STR(OFFB) \
               : "=v"(DST)                                         \
               : "v"(PTR));
#define LOADSET(S, OFFB)                                  \
  LD1(bh0##S, pdh0, OFFB) LD1(bh1##S, pdh1, OFFB)         \
  LD1(bh2##S, pdh2, OFFB) LD1(bh3##S, pdh3, OFFB)

#define MFMA_BF16 __builtin_amdgcn_mfma_f32_16x16x32_bf16
#define KSTEP_BODY(S, KS)                                        \
  {                                                              \
    const short8 ah0 = *(const short8*)(qb0 + (KS) * 64);        \
    const short8 ah1 = *(const short8*)(qb1 + (KS) * 64);        \
    a00 = MFMA_BF16(ah0, bh0##S, a00, 0, 0, 0);                  \
    a01 = MFMA_BF16(ah0, bh1##S, a01, 0, 0, 0);                  \
    a02 = MFMA_BF16(ah0, bh2##S, a02, 0, 0, 0);                  \
    a03 = MFMA_BF16(ah0, bh3##S, a03, 0, 0, 0);                  \
    a10 = MFMA_BF16(ah1, bh0##S, a10, 0, 0, 0);                  \
    a11 = MFMA_BF16(ah1, bh1##S, a11, 0, 0, 0);                  \
    a12 = MFMA_BF16(ah1, bh2##S, a12, 0, 0, 0);                  \
    a13 = MFMA_BF16(ah1, bh3##S, a13, 0, 0, 0);                  \
  }
#define WAITC(N)                                            \
  asm volatile("s_waitcnt vmcnt(" STR(N) ")" ::: "memory"); \
  __builtin_amdgcn_sched_barrier(0);

#define KSTEP(S, KS, WN) WAITC(WN) KSTEP_BODY(S, KS)

  // prologue: issue ALL 40 loads (10 sets); byte offset = ks*64
  LOADSET(A, 0)
  LOADSET(B, 64)
  LOADSET(C, 128)
  LOADSET(D, 192)
  LOADSET(E, 256)
  LOADSET(F, 320)
  LOADSET(G, 384)
  LOADSET(H, 448)
  LOADSET(I, 512)
  LOADSET(J, 576)
  // 10 K-steps, draining 4 loads each
  KSTEP(A, 0, 36)
  KSTEP(B, 1, 32)
  KSTEP(C, 2, 28)
  KSTEP(D, 3, 24)
  KSTEP(E, 4, 20)
  KSTEP(F, 5, 16)
  KSTEP(G, 6, 12)
  KSTEP(H, 7, 8)
  KSTEP(I, 8, 4)
  KSTEP(J, 9, 0)

#undef KSTEP
#undef WAITC
#undef KSTEP_BODY
#undef MFMA_BF16
#undef LOADSET
#undef LD1
#undef STR
#undef STR2

  __syncthreads();  // all waves done reading qsh; safe to overwrite with costmp

  // scatter C tiles: C col=lane&15 (token), row=kg*4+reg (q in tile)
#define WT(ACC, M, NT)                                            \
  {                                                               \
    float* dst = &costmp[wave][NT * 16 + c][M * 16 + kg * 4];     \
    dst[0] = ACC[0]; dst[1] = ACC[1];                             \
    dst[2] = ACC[2]; dst[3] = ACC[3];                             \
  }
  WT(a00, 0, 0) WT(a01, 0, 1) WT(a02, 0, 2) WT(a03, 0, 3)
  WT(a10, 1, 0) WT(a11, 1, 1) WT(a12, 1, 2) WT(a13, 1, 3)
#undef WT

  // per-wave top-20 scan over this wave's 64 tokens (R5-proven)
  if (lane < TQ) {
    const int q = lane;
    float* tv = &topv[wave][q][0];
#pragma unroll
    for (int k = 0; k < TOPK; ++k) tv[k] = -2.0f;
    float mn = -2.0f;
    for (int tt = 0; tt < 64; ++tt) {
      float v = costmp[wave][tt][q];
      if (v > mn) {
        int p = TOPK - 1;
        while (p > 0 && tv[p - 1] < v) {
          tv[p] = tv[p - 1];
          --p;
        }
        tv[p] = v;
        mn = tv[TOPK - 1];
      }
    }
  }
  __syncthreads();

  // combine 4 wave lists into topv[0]
  if (tid < TQ) {
    const int q = tid;
    float* dst = &topv[0][q][0];
#pragma unroll
    for (int w = 1; w < 4; ++w) {
      for (int k = 0; k < TOPK; ++k) {
        float v = topv[w][q][k];
        if (v <= dst[TOPK - 1]) break;
        int p = TOPK - 1;
        while (p > 0 && dst[p - 1] < v) {
          dst[p] = dst[p - 1];
          --p;
        }
        dst[p] = v;
      }
    }
  }
  __syncthreads();

  for (int i = tid; i < TQ * TOPK; i += 256)
    partial[((size_t)(b * NCHUNK + chunk)) * (TQ * TOPK) + i] =
        topv[0][i / TOPK][i % TOPK];
}

// ---------------- Fallback path (R5, proven 476us): fp32 VALU ----------------
__global__ __launch_bounds__(256) void qprep_kernel(const int* __restrict__ query,
                                                    const float* __restrict__ emb,
                                                    const float* __restrict__ invn,
                                                    float* __restrict__ qn_t) {
  const int b = blockIdx.x;
  for (int i = (int)threadIdx.x; i < NHC * TQ; i += 256) {
    int hc = i >> 5, q = i & 31;
    int tok = query[b * TQ + q];
    float inv = invn[tok];
    float4 v = *(const float4*)(emb + (size_t)tok * EMB + hc * 4);
    float4 o;
    o.x = v.x * inv; o.y = v.y * inv; o.z = v.z * inv; o.w = v.w * inv;
    *(float4*)(qn_t + (((size_t)b * NHC + hc) * TQ + q) * 4) = o;
  }
}

__global__ __launch_bounds__(256, 3) void cos_topk_kernel(
    const int* __restrict__ doc, const float* __restrict__ emb,
    const float* __restrict__ invn, const float* __restrict__ qn_t,
    float* __restrict__ partial) {
  __shared__ __align__(16) float smem_f[9600];
  __shared__ float topv[4][TQ][21];
  float* qsh = smem_f;
  float (*costmp)[33] = (float (*)[33])smem_f;

  const int b = blockIdx.y;
  const int chunk = blockIdx.x;
  const int tid = (int)threadIdx.x;
  const int wave = tid >> 6;
  const int lane = tid & 63;

  {
    const float4* src = (const float4*)(qn_t + (size_t)b * (NHC * TQ * 4));
    float4* dst = (float4*)qsh;
    for (int i = tid; i < NHC * TQ; i += 256) dst[i] = src[i];
  }
  if (lane < TQ) {
#pragma unroll
    for (int k = 0; k < TOPK; ++k) topv[wave][lane][k] = -2.0f;
  }
  __syncthreads();

  const int tok = doc[b * TD + chunk * 256 + tid];
  const float invd = invn[tok];
  const float* __restrict__ drow = emb + (size_t)tok * EMB;

  float acc[TQ];
#pragma unroll
  for (int qi = 0; qi < TQ; ++qi) acc[qi] = 0.f;

  float4 p0 = *(const float4*)(drow + 0);
  float4 p1 = *(const float4*)(drow + 4);
  float4 p2 = *(const float4*)(drow + 8);
  float4 p3 = *(const float4*)(drow + 12);
  float4 p4 = *(const float4*)(drow + 16);

#define STEP(S, PS)                                                           \
  {                                                                           \
    const float4 d = PS;                                                      \
    PS = *(const float4*)(drow + 4 * (hcb + S + 5));                          \
    const float* __restrict__ qc = qsh + (hcb + S) * (TQ * 4);                \
    _Pragma("unroll") for (int qi = 0; qi < TQ; ++qi) {                       \
      float4 qf = *(const float4*)(qc + qi * 4);                              \
      acc[qi] =                                                               \
          fmaf(qf.x, d.x, fmaf(qf.y, d.y, fmaf(qf.z, d.z, fmaf(qf.w, d.w, acc[qi])))); \
    }                                                                         \
  }
#define STEP_LAST(S, PS)                                                      \
  {                                                                           \
    const float4 d = PS;                                                      \
    const float* __restrict__ qc = qsh + (hcb + S) * (TQ * 4);                \
    _Pragma("unroll") for (int qi = 0; qi < TQ; ++qi) {                       \
      float4 qf = *(const float4*)(qc + qi * 4);                              \
      acc[qi] =                                                               \
          fmaf(qf.x, d.x, fmaf(qf.y, d.y, fmaf(qf.z, d.z, fmaf(qf.w, d.w, acc[qi])))); \
    }                                                                         \
  }
#pragma unroll 1
  for (int r = 0; r < 14; ++r) {
    const int hcb = r * 5;
    STEP(0, p0) STEP(1, p1) STEP(2, p2) STEP(3, p3) STEP(4, p4)
  }
  {
    const int hcb = 70;
    STEP_LAST(0, p0) STEP_LAST(1, p1) STEP_LAST(2, p2) STEP_LAST(3, p3) STEP_LAST(4, p4)
  }
#undef STEP
#undef STEP_LAST

  __syncthreads();
#pragma unroll
  for (int qi = 0; qi < TQ; ++qi) costmp[wave * 64 + lane][qi] = acc[qi] * invd;

  if (lane < TQ) {
    const int q = lane;
    float* tv = &topv[wave][q][0];
    float mn = tv[TOPK - 1];
    for (int tt = 0; tt < 64; ++tt) {
      float v = costmp[wave * 64 + tt][q];
      if (v > mn) {
        int p = TOPK - 1;
        while (p > 0 && tv[p - 1] < v) {
          tv[p] = tv[p - 1];
          --p;
        }
        tv[p] = v;
        mn = tv[TOPK - 1];
      }
    }
  }
  __syncthreads();

  if (tid < TQ) {
    const int q = tid;
    float* dst = &topv[0][q][0];
#pragma unroll
    for (int w = 1; w < 4; ++w) {
      for (int k = 0; k < TOPK; ++k) {
        float v = topv[w][q][k];
        if (v <= dst[TOPK - 1]) break;
        int p = TOPK - 1;
        while (p > 0 && dst[p - 1] < v) {
          dst[p] = dst[p - 1];
          --p;
        }
        dst[p] = v;
      }
    }
  }
  __syncthreads();

  for (int i = tid; i < TQ * TOPK; i += 256)
    partial[((size_t)(b * NCHUNK + chunk)) * (TQ * TOPK) + i] =
        topv[0][i / TOPK][i % TOPK];
}

// ---------------- Kernel 3: merge partials, FFW+tanh, gated softmax ----------------
__global__ __launch_bounds__(64) void finalize_kernel(
    const float* __restrict__ partial, const int* __restrict__ query,
    const float* __restrict__ qidf, const float* __restrict__ ffw_W,
    const float* __restrict__ ffw_b, const float* __restrict__ gates_W,
    const float* __restrict__ out_W, const float* __restrict__ out_b,
    float* __restrict__ out) {
  const int b = blockIdx.x;
  const int lane = (int)threadIdx.x;
  float ffw = 0.f;
  float logit = -3e38f;
  if (lane < TQ) {
    const int q = lane;
    int pos[NCHUNK];
#pragma unroll
    for (int c = 0; c < NCHUNK; ++c) pos[c] = 0;
    float s = 0.f;
    for (int k = 0; k < TOPK; ++k) {
      float best = -4.f;
      int bi = 0;
#pragma unroll
      for (int c = 0; c < NCHUNK; ++c) {
        float v = (pos[c] < TOPK)
                      ? partial[((size_t)(b * NCHUNK + c) * TQ + q) * TOPK + pos[c]]
                      : -4.f;
        if (v > best) {
          best = v;
          bi = c;
        }
      }
#pragma unroll
      for (int c = 0; c < NCHUNK; ++c)
        if (c == bi) pos[c]++;
      s += best * ffw_W[k];
    }
    ffw = tanhf(s + ffw_b[0]);
    int tok = query[b * TQ + q];
    logit = qidf[b * TQ + q] * gates_W[0] + (tok == 0 ? -1e7f : 0.f);
  }
  float m = logit;
#pragma unroll
  for (int off = 32; off; off >>= 1) m = fmaxf(m, __shfl_xor(m, off, 64));
  float e = expf(logit - m);
  float num = e * ffw;
  float den = e;
#pragma unroll
  for (int off = 32; off; off >>= 1) {
    num += __shfl_xor(num, off, 64);
    den += __shfl_xor(den, off, 64);
  }
  if (lane == 0) out[b] = (num / den) * out_W[0] + out_b[0];
}

extern "C" void kernel_launch(void* const* d_in, const int* in_sizes, int n_in,
                              void* d_out, int out_size, void* d_ws, size_t ws_size,
                              hipStream_t stream) {
  const int* doc = (const int*)d_in[0];
  const int* query = (const int*)d_in[1];
  const float* qidf = (const float*)d_in[2];
  const float* emb = (const float*)d_in[3];
  const float* ffw_W = (const float*)d_in[4];
  const float* ffw_b = (const float*)d_in[5];
  const float* gates_W = (const float*)d_in[6];
  const float* out_W = (const float*)d_in[7];
  const float* out_b = (const float*)d_in[8];
  float* out = (float*)d_out;

  char* ws = (char*)d_ws;
  float* invn = (float*)ws;  // fallback path only

  // MFMA-path layout (bytes): invn 200192 | qhi 2621440 | dhi 32000000 |
  // partial 5242880  => ~40MB total
  const size_t OFF_QHI = 200192;
  const size_t OFF_DHI = OFF_QHI + (size_t)NB * TQ * KP * 2;
  const size_t OFF_PAR = OFF_DHI + (size_t)VOCAB * KP * 2;
  const size_t NEED = OFF_PAR + (size_t)NB * NCHUNK * TQ * TOPK * 4;

  if (ws_size >= NEED) {
    ushort* qhi = (ushort*)(ws + OFF_QHI);
    ushort* dhi = (ushort*)(ws + OFF_DHI);
    float* partial = (float*)(ws + OFF_PAR);
    dprep_kernel<<<(VOCAB + 3) / 4, 256, 0, stream>>>(emb, dhi);
    qprep2_kernel<<<NB, 256, 0, stream>>>(query, emb, qhi);
    dim3 grid(NCHUNK, NB);
    mfma_topk_kernel<<<grid, 256, 0, stream>>>(doc, qhi, dhi, partial);
    finalize_kernel<<<NB, 64, 0, stream>>>(partial, query, qidf, ffw_W, ffw_b,
                                           gates_W, out_W, out_b, out);
  } else {
    // R5 fallback: invn | qn_t (1228800 f) | partial (1310720 f) ~ 10.4 MB
    float* qn_t = invn + 50048;
    float* partial = qn_t + (size_t)NB * NHC * TQ * 4;
    rownorm_kernel<<<(VOCAB + 3) / 4, 256, 0, stream>>>(emb, invn);
    qprep_kernel<<<NB, 256, 0, stream>>>(query, emb, invn, qn_t);
    dim3 grid(NCHUNK, NB);
    cos_topk_kernel<<<grid, 256, 0, stream>>>(doc, emb, invn, qn_t, partial);
    finalize_kernel<<<NB, 64, 0, stream>>>(partial, query, qidf, ffw_W, ffw_b,
                                           gates_W, out_W, out_b, out);
  }
}

// Round 15
// 297.990 us; speedup vs baseline: 1.2550x; 1.2550x over previous
//
#include <hip/hip_runtime.h>
#include <math.h>

#define VOCAB 50000
#define EMB 300
#define NB 128
#define TQ 32
#define TD 4096
#define TOPK 20
#define KP 320               // padded K (10 x 32)
#define NCHUNK 16            // doc chunks (both paths)
#define NHC 75               // EMB/4 (fallback path)
#define QSTRIDE 656          // padded LDS row stride (bytes) for q slab

typedef short short8 __attribute__((ext_vector_type(8)));
typedef float f32x4 __attribute__((ext_vector_type(4)));

// ---- RTNE float -> bf16 helper ----
__device__ inline ushort bf16_rtne(float x) {
  unsigned u = __float_as_uint(x);
  unsigned r = u + 0x7fffu + ((u >> 16) & 1u);
  return (ushort)(r >> 16);
}

// ---------------- Kernel 1 (fallback only): per-row inverse norms ----------------
__global__ __launch_bounds__(256) void rownorm_kernel(const float* __restrict__ emb,
                                                      float* __restrict__ invn) {
  int row = blockIdx.x * 4 + (threadIdx.x >> 6);
  if (row >= VOCAB) return;
  int lane = threadIdx.x & 63;
  float s = 0.f;
  for (int h = lane; h < EMB; h += 64) {
    float v = emb[row * EMB + h];
    s += v * v;
  }
#pragma unroll
  for (int off = 32; off; off >>= 1) s += __shfl_xor(s, off, 64);
  if (lane == 0) invn[row] = 1.0f / fmaxf(sqrtf(s), 1e-8f);
}

// ---------------- MFMA prep: fused norm + bf16(hi) + pad (doc table) ----------------
__global__ __launch_bounds__(256) void dprep_kernel(const float* __restrict__ emb,
                                                    ushort* __restrict__ dhi) {
  int row = blockIdx.x * 4 + (threadIdx.x >> 6);
  if (row >= VOCAB) return;
  int lane = threadIdx.x & 63;
  float v[5];
  float s = 0.f;
#pragma unroll
  for (int j = 0; j < 5; ++j) {
    int k = j * 64 + lane;
    float x = (k < EMB) ? emb[(size_t)row * EMB + k] : 0.f;
    v[j] = x;
    s += x * x;
  }
#pragma unroll
  for (int off = 32; off; off >>= 1) s += __shfl_xor(s, off, 64);
  float inv = 1.0f / fmaxf(sqrtf(s), 1e-8f);
#pragma unroll
  for (int j = 0; j < 5; ++j) {
    int k = j * 64 + lane;
    dhi[(size_t)row * KP + k] = bf16_rtne(v[j] * inv);
  }
}

__global__ __launch_bounds__(256) void qprep2_kernel(const int* __restrict__ query,
                                                     const float* __restrict__ emb,
                                                     ushort* __restrict__ qhi) {
  const int b = blockIdx.x;
  const int wave = (int)threadIdx.x >> 6;
  const int lane = (int)threadIdx.x & 63;
#pragma unroll 1
  for (int q = wave; q < TQ; q += 4) {
    int tok = query[b * TQ + q];
    float v[5];
    float s = 0.f;
#pragma unroll
    for (int j = 0; j < 5; ++j) {
      int k = j * 64 + lane;
      float x = (k < EMB) ? emb[(size_t)tok * EMB + k] : 0.f;
      v[j] = x;
      s += x * x;
    }
#pragma unroll
    for (int off = 32; off; off >>= 1) s += __shfl_xor(s, off, 64);
    float inv = 1.0f / fmaxf(sqrtf(s), 1e-8f);
#pragma unroll
    for (int j = 0; j < 5; ++j) {
      int k = j * 64 + lane;
      qhi[(size_t)(b * TQ + q) * KP + k] = bf16_rtne(v[j] * inv);
    }
  }
}

// ---------------- MFMA main: hi-only, LDS q-slab, depth-5 doc pipeline ----------------
// grid (16, NB), block 256 (4 waves). Wave: 32q x 64 tokens, 8 f32x4 acc.
// PROVEN R11 STATE (298us total, absmax 1.22e-4). Doc frag loads = volatile
// asm global_load_dwordx4, 5 sets x 4 loads, steady state 20 outstanding,
// s_waitcnt vmcnt(16) per step (drain only in tail). Q frags from a 21KB LDS
// slab (stride 656B). Epilogue dumps all accs to LDS immediately after the
// final vmcnt(0) -- do NOT restructure into acc-live sub-passes (R13/R14:
// codegen-sensitive corruption). Do NOT tighten launch_bounds below (256,3)
// (R13: allocator spills asm-pinned in-flight load dests -> NaN).
__global__ __launch_bounds__(256, 3) void mfma_topk_kernel(
    const int* __restrict__ doc, const ushort* __restrict__ qhi,
    const ushort* __restrict__ dhi, float* __restrict__ partial) {
  __shared__ __align__(16) char smem[33792];  // qsh (20992B), later costmp
  __shared__ float topv[4][TQ][21];

  float (*costmp)[64][33] = (float (*)[64][33])smem;  // [wave][token][q]

  const int b = blockIdx.y;
  const int chunk = blockIdx.x;
  const int tid = (int)threadIdx.x;
  const int wave = tid >> 6;
  const int lane = tid & 63;
  const int c = lane & 15;
  const int kg = lane >> 4;

  // stage this batch's q-hi slab into LDS (coalesced short8, padded stride)
  {
    const ushort* qsrc = qhi + (size_t)b * TQ * KP;
    for (int i = tid; i < TQ * (KP / 8); i += 256) {
      int row = i / (KP / 8), j = i - row * (KP / 8);
      *(short8*)(smem + row * QSTRIDE + j * 16) =
          *(const short8*)(qsrc + row * KP + j * 8);
    }
  }
  __syncthreads();  // qsh ready

  const int tbase = b * TD + chunk * 256 + wave * 64;
  const ushort* pdh0 = dhi + (size_t)doc[tbase + 0 * 16 + c] * KP + kg * 8;
  const ushort* pdh1 = dhi + (size_t)doc[tbase + 1 * 16 + c] * KP + kg * 8;
  const ushort* pdh2 = dhi + (size_t)doc[tbase + 2 * 16 + c] * KP + kg * 8;
  const ushort* pdh3 = dhi + (size_t)doc[tbase + 3 * 16 + c] * KP + kg * 8;
  const char* qb0 = smem + c * QSTRIDE + kg * 16;
  const char* qb1 = smem + (16 + c) * QSTRIDE + kg * 16;

  f32x4 a00 = {0.f, 0.f, 0.f, 0.f}, a01 = a00, a02 = a00, a03 = a00;
  f32x4 a10 = a00, a11 = a00, a12 = a00, a13 = a00;

  short8 bh0A, bh1A, bh2A, bh3A, bh0B, bh1B, bh2B, bh3B, bh0C, bh1C, bh2C,
      bh3C, bh0D, bh1D, bh2D, bh3D, bh0E, bh1E, bh2E, bh3E;

#define STR2(x) #x
#define STR(x) STR2(x)
#define LD1(DST, PTR, OFFB)                                        \
  asm volatile("global_load_dwordx4 %0, %1, off offset:" STR(OFFB) \
               : "=v"(DST)                                         \
               : "v"(PTR));
#define LOADSET(S, OFFB)                                  \
  LD1(bh0##S, pdh0, OFFB) LD1(bh1##S, pdh1, OFFB)         \
  LD1(bh2##S, pdh2, OFFB) LD1(bh3##S, pdh3, OFFB)

#define MFMA_BF16 __builtin_amdgcn_mfma_f32_16x16x32_bf16
#define KSTEP_BODY(S, KS)                                        \
  {                                                              \
    const short8 ah0 = *(const short8*)(qb0 + (KS) * 64);        \
    const short8 ah1 = *(const short8*)(qb1 + (KS) * 64);        \
    a00 = MFMA_BF16(ah0, bh0##S, a00, 0, 0, 0);                  \
    a01 = MFMA_BF16(ah0, bh1##S, a01, 0, 0, 0);                  \
    a02 = MFMA_BF16(ah0, bh2##S, a02, 0, 0, 0);                  \
    a03 = MFMA_BF16(ah0, bh3##S, a03, 0, 0, 0);                  \
    a10 = MFMA_BF16(ah1, bh0##S, a10, 0, 0, 0);                  \
    a11 = MFMA_BF16(ah1, bh1##S, a11, 0, 0, 0);                  \
    a12 = MFMA_BF16(ah1, bh2##S, a12, 0, 0, 0);                  \
    a13 = MFMA_BF16(ah1, bh3##S, a13, 0, 0, 0);                  \
  }
#define WAITC(N)                                            \
  asm volatile("s_waitcnt vmcnt(" STR(N) ")" ::: "memory"); \
  __builtin_amdgcn_sched_barrier(0);

#define KSTEP_R(S, KS, WN, RKS) WAITC(WN) KSTEP_BODY(S, KS) LOADSET(S, RKS)
#define KSTEP_N(S, KS, WN) WAITC(WN) KSTEP_BODY(S, KS)

  // prologue: fill depth-5 pipeline (20 loads in flight)
  LOADSET(A, 0)
  LOADSET(B, 64)
  LOADSET(C, 128)
  LOADSET(D, 192)
  LOADSET(E, 256)
  // 10 K-steps; byte offset = ks*64
  KSTEP_R(A, 0, 16, 320)
  KSTEP_R(B, 1, 16, 384)
  KSTEP_R(C, 2, 16, 448)
  KSTEP_R(D, 3, 16, 512)
  KSTEP_R(E, 4, 16, 576)
  KSTEP_N(A, 5, 16)
  KSTEP_N(B, 6, 12)
  KSTEP_N(C, 7, 8)
  KSTEP_N(D, 8, 4)
  KSTEP_N(E, 9, 0)

#undef KSTEP_R
#undef KSTEP_N
#undef WAITC
#undef KSTEP_BODY
#undef MFMA_BF16
#undef LOADSET
#undef LD1
#undef STR
#undef STR2

  __syncthreads();  // all waves done reading qsh; safe to overwrite with costmp

  // scatter C tiles: C col=lane&15 (token), row=kg*4+reg (q in tile)
#define WT(ACC, M, NT)                                            \
  {                                                               \
    float* dst = &costmp[wave][NT * 16 + c][M * 16 + kg * 4];     \
    dst[0] = ACC[0]; dst[1] = ACC[1];                             \
    dst[2] = ACC[2]; dst[3] = ACC[3];                             \
  }
  WT(a00, 0, 0) WT(a01, 0, 1) WT(a02, 0, 2) WT(a03, 0, 3)
  WT(a10, 1, 0) WT(a11, 1, 1) WT(a12, 1, 2) WT(a13, 1, 3)
#undef WT

  // per-wave top-20 scan over this wave's 64 tokens (R5-proven)
  if (lane < TQ) {
    const int q = lane;
    float* tv = &topv[wave][q][0];
#pragma unroll
    for (int k = 0; k < TOPK; ++k) tv[k] = -2.0f;
    float mn = -2.0f;
    for (int tt = 0; tt < 64; ++tt) {
      float v = costmp[wave][tt][q];
      if (v > mn) {
        int p = TOPK - 1;
        while (p > 0 && tv[p - 1] < v) {
          tv[p] = tv[p - 1];
          --p;
        }
        tv[p] = v;
        mn = tv[TOPK - 1];
      }
    }
  }
  __syncthreads();

  // combine 4 wave lists into topv[0]
  if (tid < TQ) {
    const int q = tid;
    float* dst = &topv[0][q][0];
#pragma unroll
    for (int w = 1; w < 4; ++w) {
      for (int k = 0; k < TOPK; ++k) {
        float v = topv[w][q][k];
        if (v <= dst[TOPK - 1]) break;
        int p = TOPK - 1;
        while (p > 0 && dst[p - 1] < v) {
          dst[p] = dst[p - 1];
          --p;
        }
        dst[p] = v;
      }
    }
  }
  __syncthreads();

  for (int i = tid; i < TQ * TOPK; i += 256)
    partial[((size_t)(b * NCHUNK + chunk)) * (TQ * TOPK) + i] =
        topv[0][i / TOPK][i % TOPK];
}

// ---------------- Fallback path (R5, proven 476us): fp32 VALU ----------------
__global__ __launch_bounds__(256) void qprep_kernel(const int* __restrict__ query,
                                                    const float* __restrict__ emb,
                                                    const float* __restrict__ invn,
                                                    float* __restrict__ qn_t) {
  const int b = blockIdx.x;
  for (int i = (int)threadIdx.x; i < NHC * TQ; i += 256) {
    int hc = i >> 5, q = i & 31;
    int tok = query[b * TQ + q];
    float inv = invn[tok];
    float4 v = *(const float4*)(emb + (size_t)tok * EMB + hc * 4);
    float4 o;
    o.x = v.x * inv; o.y = v.y * inv; o.z = v.z * inv; o.w = v.w * inv;
    *(float4*)(qn_t + (((size_t)b * NHC + hc) * TQ + q) * 4) = o;
  }
}

__global__ __launch_bounds__(256, 3) void cos_topk_kernel(
    const int* __restrict__ doc, const float* __restrict__ emb,
    const float* __restrict__ invn, const float* __restrict__ qn_t,
    float* __restrict__ partial) {
  __shared__ __align__(16) float smem_f[9600];
  __shared__ float topv[4][TQ][21];
  float* qsh = smem_f;
  float (*costmp)[33] = (float (*)[33])smem_f;

  const int b = blockIdx.y;
  const int chunk = blockIdx.x;
  const int tid = (int)threadIdx.x;
  const int wave = tid >> 6;
  const int lane = tid & 63;

  {
    const float4* src = (const float4*)(qn_t + (size_t)b * (NHC * TQ * 4));
    float4* dst = (float4*)qsh;
    for (int i = tid; i < NHC * TQ; i += 256) dst[i] = src[i];
  }
  if (lane < TQ) {
#pragma unroll
    for (int k = 0; k < TOPK; ++k) topv[wave][lane][k] = -2.0f;
  }
  __syncthreads();

  const int tok = doc[b * TD + chunk * 256 + tid];
  const float invd = invn[tok];
  const float* __restrict__ drow = emb + (size_t)tok * EMB;

  float acc[TQ];
#pragma unroll
  for (int qi = 0; qi < TQ; ++qi) acc[qi] = 0.f;

  float4 p0 = *(const float4*)(drow + 0);
  float4 p1 = *(const float4*)(drow + 4);
  float4 p2 = *(const float4*)(drow + 8);
  float4 p3 = *(const float4*)(drow + 12);
  float4 p4 = *(const float4*)(drow + 16);

#define STEP(S, PS)                                                           \
  {                                                                           \
    const float4 d = PS;                                                      \
    PS = *(const float4*)(drow + 4 * (hcb + S + 5));                          \
    const float* __restrict__ qc = qsh + (hcb + S) * (TQ * 4);                \
    _Pragma("unroll") for (int qi = 0; qi < TQ; ++qi) {                       \
      float4 qf = *(const float4*)(qc + qi * 4);                              \
      acc[qi] =                                                               \
          fmaf(qf.x, d.x, fmaf(qf.y, d.y, fmaf(qf.z, d.z, fmaf(qf.w, d.w, acc[qi])))); \
    }                                                                         \
  }
#define STEP_LAST(S, PS)                                                      \
  {                                                                           \
    const float4 d = PS;                                                      \
    const float* __restrict__ qc = qsh + (hcb + S) * (TQ * 4);                \
    _Pragma("unroll") for (int qi = 0; qi < TQ; ++qi) {                       \
      float4 qf = *(const float4*)(qc + qi * 4);                              \
      acc[qi] =                                                               \
          fmaf(qf.x, d.x, fmaf(qf.y, d.y, fmaf(qf.z, d.z, fmaf(qf.w, d.w, acc[qi])))); \
    }                                                                         \
  }
#pragma unroll 1
  for (int r = 0; r < 14; ++r) {
    const int hcb = r * 5;
    STEP(0, p0) STEP(1, p1) STEP(2, p2) STEP(3, p3) STEP(4, p4)
  }
  {
    const int hcb = 70;
    STEP_LAST(0, p0) STEP_LAST(1, p1) STEP_LAST(2, p2) STEP_LAST(3, p3) STEP_LAST(4, p4)
  }
#undef STEP
#undef STEP_LAST

  __syncthreads();
#pragma unroll
  for (int qi = 0; qi < TQ; ++qi) costmp[wave * 64 + lane][qi] = acc[qi] * invd;

  if (lane < TQ) {
    const int q = lane;
    float* tv = &topv[wave][q][0];
    float mn = tv[TOPK - 1];
    for (int tt = 0; tt < 64; ++tt) {
      float v = costmp[wave * 64 + tt][q];
      if (v > mn) {
        int p = TOPK - 1;
        while (p > 0 && tv[p - 1] < v) {
          tv[p] = tv[p - 1];
          --p;
        }
        tv[p] = v;
        mn = tv[TOPK - 1];
      }
    }
  }
  __syncthreads();

  if (tid < TQ) {
    const int q = tid;
    float* dst = &topv[0][q][0];
#pragma unroll
    for (int w = 1; w < 4; ++w) {
      for (int k = 0; k < TOPK; ++k) {
        float v = topv[w][q][k];
        if (v <= dst[TOPK - 1]) break;
        int p = TOPK - 1;
        while (p > 0 && dst[p - 1] < v) {
          dst[p] = dst[p - 1];
          --p;
        }
        dst[p] = v;
      }
    }
  }
  __syncthreads();

  for (int i = tid; i < TQ * TOPK; i += 256)
    partial[((size_t)(b * NCHUNK + chunk)) * (TQ * TOPK) + i] =
        topv[0][i / TOPK][i % TOPK];
}

// ---------------- Kernel 3: merge partials, FFW+tanh, gated softmax ----------------
__global__ __launch_bounds__(64) void finalize_kernel(
    const float* __restrict__ partial, const int* __restrict__ query,
    const float* __restrict__ qidf, const float* __restrict__ ffw_W,
    const float* __restrict__ ffw_b, const float* __restrict__ gates_W,
    const float* __restrict__ out_W, const float* __restrict__ out_b,
    float* __restrict__ out) {
  const int b = blockIdx.x;
  const int lane = (int)threadIdx.x;
  float ffw = 0.f;
  float logit = -3e38f;
  if (lane < TQ) {
    const int q = lane;
    int pos[NCHUNK];
#pragma unroll
    for (int c = 0; c < NCHUNK; ++c) pos[c] = 0;
    float s = 0.f;
    for (int k = 0; k < TOPK; ++k) {
      float best = -4.f;
      int bi = 0;
#pragma unroll
      for (int c = 0; c < NCHUNK; ++c) {
        float v = (pos[c] < TOPK)
                      ? partial[((size_t)(b * NCHUNK + c) * TQ + q) * TOPK + pos[c]]
                      : -4.f;
        if (v > best) {
          best = v;
          bi = c;
        }
      }
#pragma unroll
      for (int c = 0; c < NCHUNK; ++c)
        if (c == bi) pos[c]++;
      s += best * ffw_W[k];
    }
    ffw = tanhf(s + ffw_b[0]);
    int tok = query[b * TQ + q];
    logit = qidf[b * TQ + q] * gates_W[0] + (tok == 0 ? -1e7f : 0.f);
  }
  float m = logit;
#pragma unroll
  for (int off = 32; off; off >>= 1) m = fmaxf(m, __shfl_xor(m, off, 64));
  float e = expf(logit - m);
  float num = e * ffw;
  float den = e;
#pragma unroll
  for (int off = 32; off; off >>= 1) {
    num += __shfl_xor(num, off, 64);
    den += __shfl_xor(den, off, 64);
  }
  if (lane == 0) out[b] = (num / den) * out_W[0] + out_b[0];
}

extern "C" void kernel_launch(void* const* d_in, const int* in_sizes, int n_in,
                              void* d_out, int out_size, void* d_ws, size_t ws_size,
                              hipStream_t stream) {
  const int* doc = (const int*)d_in[0];
  const int* query = (const int*)d_in[1];
  const float* qidf = (const float*)d_in[2];
  const float* emb = (const float*)d_in[3];
  const float* ffw_W = (const float*)d_in[4];
  const float* ffw_b = (const float*)d_in[5];
  const float* gates_W = (const float*)d_in[6];
  const float* out_W = (const float*)d_in[7];
  const float* out_b = (const float*)d_in[8];
  float* out = (float*)d_out;

  char* ws = (char*)d_ws;
  float* invn = (float*)ws;  // fallback path only

  // MFMA-path layout (bytes): invn 200192 | qhi 2621440 | dhi 32000000 |
  // partial 5242880  => ~40MB total
  const size_t OFF_QHI = 200192;
  const size_t OFF_DHI = OFF_QHI + (size_t)NB * TQ * KP * 2;
  const size_t OFF_PAR = OFF_DHI + (size_t)VOCAB * KP * 2;
  const size_t NEED = OFF_PAR + (size_t)NB * NCHUNK * TQ * TOPK * 4;

  if (ws_size >= NEED) {
    ushort* qhi = (ushort*)(ws + OFF_QHI);
    ushort* dhi = (ushort*)(ws + OFF_DHI);
    float* partial = (float*)(ws + OFF_PAR);
    dprep_kernel<<<(VOCAB + 3) / 4, 256, 0, stream>>>(emb, dhi);
    qprep2_kernel<<<NB, 256, 0, stream>>>(query, emb, qhi);
    dim3 grid(NCHUNK, NB);
    mfma_topk_kernel<<<grid, 256, 0, stream>>>(doc, qhi, dhi, partial);
    finalize_kernel<<<NB, 64, 0, stream>>>(partial, query, qidf, ffw_W, ffw_b,
                                           gates_W, out_W, out_b, out);
  } else {
    // R5 fallback: invn | qn_t (1228800 f) | partial (1310720 f) ~ 10.4 MB
    float* qn_t = invn + 50048;
    float* partial = qn_t + (size_t)NB * NHC * TQ * 4;
    rownorm_kernel<<<(VOCAB + 3) / 4, 256, 0, stream>>>(emb, invn);
    qprep_kernel<<<NB, 256, 0, stream>>>(query, emb, invn, qn_t);
    dim3 grid(NCHUNK, NB);
    cos_topk_kernel<<<grid, 256, 0, stream>>>(doc, emb, invn, qn_t, partial);
    finalize_kernel<<<NB, 64, 0, stream>>>(partial, query, qidf, ffw_W, ffw_b,
                                           gates_W, out_W, out_b, out);
  }
}